// Round 5
// baseline (1968.625 us; speedup 1.0000x reference)
//
#include <hip/hip_runtime.h>
#include <math.h>

#define BB 4
#define Cc 64
#define C2 128
#define C6 384
#define HW 65536
#define EPS 1e-6f
#define CST 68      // padded LDS channel stride (patch kernel)
#define XT 256      // x-tile stride: 256 positions/tile; accesses vary along t -> 2-way banks (free)
#define OSPLIT 4    // output-channel split across blocks
#define OGPB 12     // 48/OSPLIT og-groups (of 8 channels) per block

// ---------------- K0: RoPE table: tab[r*32+m] = (cos(r*inv[m]), sin(r*inv[m])) ----------------
__global__ void k_tab(float2* __restrict__ tab) {
    int idx = blockIdx.x * 256 + threadIdx.x;   // 8192 entries
    if (idx >= 256 * 32) return;
    int r = idx >> 5, m = idx & 31;
    float inv = expf(-((2.0f * (float)m) / 64.0f) * logf(10000.0f));
    float s, c;
    sincosf((float)r * inv, &s, &c);
    tab[idx] = make_float2(c, s);
}

// ---------------- K0b: transpose w_proj (64x128) -> wpt (128x64) ----------------
__global__ void k_wt(const float* __restrict__ wp, float* __restrict__ wpt) {
    int t = blockIdx.x * 256 + threadIdx.x;
    if (t >= 64 * 128) return;
    int o = t >> 7, cc = t & 127;
    wpt[cc * 64 + o] = wp[o * 128 + cc];
}

// ---------------- K1: fused 1x1 expand + depthwise 3x3, rows [r0, r0+R), 96 out-ch per block --
// Tile: 16x16 positions (14x14 interior + 1-halo).
// R3: backend refuses to keep x[64] in VGPRs (VGPR=52 even with waves_per_eu(4,4)) and
// re-issues the 64 x-loads per ogl iter -> latency-bound. Fix: stage x-tile in LDS once.
// R4 post-mortem: xs stride was 68 but t spans 256 -> OOB LDS write, wrong results.
// R5: xs[64][256] = 64KB (total 72KB LDS, 2 blocks/CU on 160KB). i-outer/oo-inner:
// one ds_read_b32 feeds 8 FMA chains; weights wave-uniform -> s_loads on scalar pipe.
__global__ __launch_bounds__(256) void k_expdw(const float* __restrict__ xb,
                                               const float* __restrict__ wh,
                                               const float* __restrict__ wdw,
                                               float* __restrict__ h2s,
                                               int r0, int R, int tiles_y) {
    __shared__ float xs[64 * XT];
    __shared__ float hs[8 * 256];
    int t = threadIdx.x;
    int tx = t & 15, ty = t >> 4;
    int blk = blockIdx.x;
    int txi = blk % 19;
    int rest = blk / 19;
    int tyi = rest % tiles_y;
    int os = rest / tiles_y;
    int r = r0 + tyi * 14 - 1 + ty;
    int c = txi * 14 - 1 + tx;
    int rcl = min(max(r, 0), 255), ccl = min(max(c, 0), 255);

    // stage x tile: xs[i][t], one global read of x per block
    {
        const float* xp = xb + rcl * 256 + ccl;
#pragma unroll 8
        for (int i = 0; i < 64; i++) xs[i * XT + t] = xp[(size_t)i * HW];
    }
    __syncthreads();

    bool interior = (ty >= 1 && ty <= 14 && tx >= 1 && tx <= 14 &&
                     r < r0 + R && r < 256 && c < 256);
    size_t SR = (size_t)R * 256;
    for (int ogl = 0; ogl < OGPB; ogl++) {
        int og = os * OGPB + ogl;
        {
            const float* wbase = wh + (og * 8) * 64;   // 8 rows of 64 weights (uniform)
            float acc0 = 0.f, acc1 = 0.f, acc2 = 0.f, acc3 = 0.f;
            float acc4 = 0.f, acc5 = 0.f, acc6 = 0.f, acc7 = 0.f;
#pragma unroll 16
            for (int i = 0; i < 64; i++) {
                float xv = xs[i * XT + t];
                acc0 = fmaf(wbase[0 * 64 + i], xv, acc0);
                acc1 = fmaf(wbase[1 * 64 + i], xv, acc1);
                acc2 = fmaf(wbase[2 * 64 + i], xv, acc2);
                acc3 = fmaf(wbase[3 * 64 + i], xv, acc3);
                acc4 = fmaf(wbase[4 * 64 + i], xv, acc4);
                acc5 = fmaf(wbase[5 * 64 + i], xv, acc5);
                acc6 = fmaf(wbase[6 * 64 + i], xv, acc6);
                acc7 = fmaf(wbase[7 * 64 + i], xv, acc7);
            }
            hs[0 * 256 + t] = acc0;
            hs[1 * 256 + t] = acc1;
            hs[2 * 256 + t] = acc2;
            hs[3 * 256 + t] = acc3;
            hs[4 * 256 + t] = acc4;
            hs[5 * 256 + t] = acc5;
            hs[6 * 256 + t] = acc6;
            hs[7 * 256 + t] = acc7;
        }
        __syncthreads();
        if (interior) {
#pragma unroll
            for (int oo = 0; oo < 8; oo++) {
                int o = og * 8 + oo;
                const float* wk = wdw + o * 9;
                float acc = 0.f;
#pragma unroll
                for (int dr = -1; dr <= 1; dr++) {
                    int rr = r + dr;
                    if (rr < 0 || rr > 255) continue;
#pragma unroll
                    for (int dc = -1; dc <= 1; dc++) {
                        int cc2 = c + dc;
                        if (cc2 < 0 || cc2 > 255) continue;
                        acc = fmaf(wk[(dr + 1) * 3 + dc + 1],
                                   hs[oo * 256 + (ty + dr) * 16 + tx + dc], acc);
                    }
                }
                h2s[(size_t)o * SR + (size_t)(r - r0) * 256 + c] = acc;
            }
        }
        __syncthreads();
    }
}

// ---------------- K2: fused per-patch: RMS+RoPE(q,k) -> circ-conv -> RMS -> *v -> project ------
__global__ __launch_bounds__(256, 2) void k_patch(const float* __restrict__ h2s,
                                                  const float* __restrict__ gq,
                                                  const float* __restrict__ gk,
                                                  const float* __restrict__ gn,
                                                  const float* __restrict__ wpt,
                                                  const float2* __restrict__ tab,
                                                  float* __restrict__ outb,
                                                  int r0, int R) {
    __shared__ float qs[C2 * CST];
    __shared__ float ks[C2 * CST];
    __shared__ float part[256], part2[256];
    __shared__ float sq[64], sk[64], scal[64];
    int t = threadIdx.x;
    int p = blockIdx.x;                 // (R/8)*32 patches
    int prs = p >> 5, pc = p & 31;
    size_t SR = (size_t)R * 256;
    size_t sb = (size_t)(prs * 8) * 256 + pc * 8;
    const float* qg = h2s + sb;
    const float* kg = h2s + 128 * SR + sb;
    const float* vg = h2s + 256 * SR + sb;

    // phase 1: load q,k patch to LDS
    for (int it = 0; it < 8; it++) {
        int l4 = it * 256 + t;
        int c = l4 >> 4, r4 = l4 & 15;
        int i = r4 >> 1, jq = r4 & 1;
        *(float4*)&qs[c * CST + i * 8 + jq * 4] = *(const float4*)(qg + (size_t)c * SR + i * 256 + jq * 4);
        *(float4*)&ks[c * CST + i * 8 + jq * 4] = *(const float4*)(kg + (size_t)c * SR + i * 256 + jq * 4);
    }
    __syncthreads();

    // phase 1b: per-position channel sums of q^2, k^2
    {
        int pos = t & 63, grp = t >> 6;
        float s1 = 0.f, s2 = 0.f;
        for (int c = grp * 32; c < grp * 32 + 32; c++) {
            float a = qs[c * CST + pos]; s1 = fmaf(a, a, s1);
            float e = ks[c * CST + pos]; s2 = fmaf(e, e, s2);
        }
        part[grp * 64 + pos] = s1;
        part2[grp * 64 + pos] = s2;
    }
    __syncthreads();
    if (t < 64) {
        sq[t] = rsqrtf((part[t] + part[64 + t] + part[128 + t] + part[192 + t]) * (1.f / 128.f) + EPS);
    } else if (t < 128) {
        int u = t - 64;
        sk[u] = rsqrtf((part2[u] + part2[64 + u] + part2[128 + u] + part2[192 + u]) * (1.f / 128.f) + EPS);
    }
    __syncthreads();

    // phase 1c: RMS-scale + RoPE in place (pairs 2m,2m+1)
    for (int u = 0; u < 16; u++) {
        int task = u * 256 + t;
        int m = task >> 6, pos = task & 63;
        int i = pos >> 3, j = pos & 7;
        float2 cs = (m < 32) ? tab[(r0 + prs * 8 + i) * 32 + m]
                             : tab[(pc * 8 + j) * 32 + (m - 32)];
        float sqp = sq[pos], skp = sk[pos];
        float q0 = qs[(2 * m) * CST + pos], q1 = qs[(2 * m + 1) * CST + pos];
        float y0 = gq[2 * m] * q0 * sqp, y1 = gq[2 * m + 1] * q1 * sqp;
        qs[(2 * m) * CST + pos] = y0 * cs.x - y1 * cs.y;
        qs[(2 * m + 1) * CST + pos] = y1 * cs.x + y0 * cs.y;
        float k0 = ks[(2 * m) * CST + pos], k1 = ks[(2 * m + 1) * CST + pos];
        float z0 = gk[2 * m] * k0 * skp, z1 = gk[2 * m + 1] * k1 * skp;
        ks[(2 * m) * CST + pos] = z0 * cs.x - z1 * cs.y;
        ks[(2 * m + 1) * CST + pos] = z1 * cs.x + z0 * cs.y;
    }
    __syncthreads();

    // phase 2: circular conv rows -> registers (task = (c, m), 4 per thread; UNROLLED so creg
    // stays in VGPRs, not scratch)
    float creg[4][8];
#pragma unroll
    for (int g4 = 0; g4 < 4; g4++) {
        int task = g4 * 256 + t;
        int c = task >> 3, m = task & 7;
        float o8[8] = {0, 0, 0, 0, 0, 0, 0, 0};
#pragma unroll
        for (int i = 0; i < 8; i++) {
            const float* qr = &qs[c * CST + i * 8];
            float4 qa = *(const float4*)qr, qb = *(const float4*)(qr + 4);
            float qq[8] = {qa.x, qa.y, qa.z, qa.w, qb.x, qb.y, qb.z, qb.w};
            int kr = (m - i) & 7;
            const float* krp = &ks[c * CST + kr * 8];
            float4 ka = *(const float4*)krp, kb2 = *(const float4*)(krp + 4);
            float kk[8] = {ka.x, ka.y, ka.z, ka.w, kb2.x, kb2.y, kb2.z, kb2.w};
#pragma unroll
            for (int n = 0; n < 8; n++)
#pragma unroll
                for (int j = 0; j < 8; j++)
                    o8[n] = fmaf(qq[j], kk[(n - j) & 7], o8[n]);
        }
#pragma unroll
        for (int n = 0; n < 8; n++) creg[g4][n] = o8[n];
    }
    __syncthreads();

    // phase 3: store corr over qs
#pragma unroll
    for (int g4 = 0; g4 < 4; g4++) {
        int task = g4 * 256 + t;
        int c = task >> 3, m = task & 7;
        *(float4*)&qs[c * CST + m * 8] =
            make_float4(creg[g4][0], creg[g4][1], creg[g4][2], creg[g4][3]);
        *(float4*)&qs[c * CST + m * 8 + 4] =
            make_float4(creg[g4][4], creg[g4][5], creg[g4][6], creg[g4][7]);
    }
    __syncthreads();

    // phase 4: per-position sum of corr^2 over channels
    {
        int pos = t & 63, q4 = t >> 6;
        float ssum = 0.f;
        for (int c = q4 * 32; c < q4 * 32 + 32; c++) {
            float v = qs[c * CST + pos];
            ssum = fmaf(v, v, ssum);
        }
        part[q4 * 64 + pos] = ssum;
    }
    __syncthreads();
    if (t < 64) {
        float s = part[t] + part[64 + t] + part[128 + t] + part[192 + t];
        scal[t] = rsqrtf(s * (1.0f / 128.f) + EPS);
    }
    __syncthreads();

    // phase 5: tmod in place: qs[c][pos] = corr*scal[pos]*gn[c]*v[c][pos]
    for (int it = 0; it < 8; it++) {
        int l4 = it * 256 + t;
        int c = l4 >> 4, r4 = l4 & 15;
        int i = r4 >> 1, jq = r4 & 1;
        float4 vv = *(const float4*)(vg + (size_t)c * SR + i * 256 + jq * 4);
        float4 sc4 = *(const float4*)&scal[r4 * 4];
        float g = gn[c];
        float4 cu = *(float4*)&qs[c * CST + r4 * 4];
        cu.x = cu.x * sc4.x * g * vv.x;
        cu.y = cu.y * sc4.y * g * vv.y;
        cu.z = cu.z * sc4.z * g * vv.z;
        cu.w = cu.w * sc4.w * g * vv.w;
        *(float4*)&qs[c * CST + r4 * 4] = cu;
    }
    __syncthreads();

    // phase 6: project 128->64, stage to ks as out_s[pos*CST + o]
    {
        int o = t & 63, pg = t >> 6;
        float acc[16];
#pragma unroll
        for (int u = 0; u < 16; u++) acc[u] = 0.f;
        for (int c = 0; c < C2; c++) {
            float w = wpt[c * 64 + o];
            const float* tp = &qs[c * CST + pg * 16];
#pragma unroll
            for (int u4 = 0; u4 < 4; u4++) {
                float4 tv = *(const float4*)(tp + u4 * 4);
                acc[u4 * 4 + 0] = fmaf(w, tv.x, acc[u4 * 4 + 0]);
                acc[u4 * 4 + 1] = fmaf(w, tv.y, acc[u4 * 4 + 1]);
                acc[u4 * 4 + 2] = fmaf(w, tv.z, acc[u4 * 4 + 2]);
                acc[u4 * 4 + 3] = fmaf(w, tv.w, acc[u4 * 4 + 3]);
            }
        }
#pragma unroll
        for (int u = 0; u < 16; u++) ks[(pg * 16 + u) * CST + o] = acc[u];
    }
    __syncthreads();

    // phase 7: coalesced out write
    float* og = outb + (size_t)r0 * 256 + sb;
    for (int it = 0; it < 4; it++) {
        int l4 = it * 256 + t;
        int o = l4 >> 4, r4 = l4 & 15;
        int i = r4 >> 1, jq = r4 & 1;
        int p0 = i * 8 + jq * 4;
        float4 vv = make_float4(ks[(p0 + 0) * CST + o], ks[(p0 + 1) * CST + o],
                                ks[(p0 + 2) * CST + o], ks[(p0 + 3) * CST + o]);
        *(float4*)(og + (size_t)o * HW + i * 256 + jq * 4) = vv;
    }
}

extern "C" void kernel_launch(void* const* d_in, const int* in_sizes, int n_in,
                              void* d_out, int out_size, void* d_ws, size_t ws_size,
                              hipStream_t stream) {
    const float* x   = (const float*)d_in[0];
    const float* wh  = (const float*)d_in[1];
    const float* wdw = (const float*)d_in[2];
    const float* wp  = (const float*)d_in[3];
    const float* gn  = (const float*)d_in[4];
    const float* gq  = (const float*)d_in[5];
    const float* gk  = (const float*)d_in[6];
    float* out = (float*)d_out;

    // ws layout (floats): tab[16384] | wpt[8192] | h2s[384 * R * 256]
    size_t avail = ws_size / 4;
    if (avail < (size_t)24576 + (size_t)C6 * 8 * 256) return;  // need at least R=8
    size_t rows_cap = (avail - 24576) / ((size_t)C6 * 256);
    int R = (rows_cap >= 256) ? 256 : (int)(rows_cap & ~(size_t)7);

    float* ws = (float*)d_ws;
    float2* tab = (float2*)ws;
    float* wpt  = ws + 16384;
    float* h2s  = ws + 24576;

    k_tab<<<32, 256, 0, stream>>>(tab);
    k_wt<<<32, 256, 0, stream>>>(wp, wpt);
    for (int b = 0; b < BB; b++) {
        const float* xb = x + (size_t)b * Cc * HW;
        float* outb = out + (size_t)b * Cc * HW;
        for (int r0 = 0; r0 < 256; r0 += R) {
            int Rc = (256 - r0 < R) ? (256 - r0) : R;
            int tiles_y = (Rc + 13) / 14;
            k_expdw<<<19 * tiles_y * OSPLIT, 256, 0, stream>>>(xb, wh, wdw, h2s, r0, Rc, tiles_y);
            k_patch<<<(Rc / 8) * 32, 256, 0, stream>>>(h2s, gq, gk, gn, wpt, tab, outb, r0, Rc);
        }
    }
}

// Round 6
// 1374.978 us; speedup vs baseline: 1.4318x; 1.4318x over previous
//
#include <hip/hip_runtime.h>
#include <math.h>

#define BB 4
#define Cc 64
#define C2 128
#define C6 384
#define HW 65536
#define EPS 1e-6f
#define CST 68      // padded LDS channel stride (patch kernel)
#define OSPLIT 8    // output-channel split across blocks
#define CHB 48      // channels per block = 384/OSPLIT
#define HST 52      // hs row stride (floats): 16B-aligned; quad-starts tile banks -> conflict-free b128

// ---------------- K0: RoPE table: tab[r*32+m] = (cos(r*inv[m]), sin(r*inv[m])) ----------------
__global__ void k_tab(float2* __restrict__ tab) {
    int idx = blockIdx.x * 256 + threadIdx.x;   // 8192 entries
    if (idx >= 256 * 32) return;
    int r = idx >> 5, m = idx & 31;
    float inv = expf(-((2.0f * (float)m) / 64.0f) * logf(10000.0f));
    float s, c;
    sincosf((float)r * inv, &s, &c);
    tab[idx] = make_float2(c, s);
}

// ---------------- K0b: transpose w_proj (64x128) -> wpt (128x64) ----------------
__global__ void k_wt(const float* __restrict__ wp, float* __restrict__ wpt) {
    int t = blockIdx.x * 256 + threadIdx.x;
    if (t >= 64 * 128) return;
    int o = t >> 7, cc = t & 127;
    wpt[cc * 64 + o] = wp[o * 128 + cc];
}

// ---------------- K1: fused 1x1 expand + depthwise 3x3, rows [r0, r0+R), 48 out-ch per block --
// R5 post-mortem: xs-in-LDS killed occupancy (2 blk/CU) while keeping 24 barrier drains ->
// VALUBusy 20%, 420us. R6: streaming one-pass design.
//  - 48 accumulators/thread (RA cannot rematerialize accumulators -> no reload pathology).
//  - x streamed ONCE per thread in 8-float chunks; each chunk feeds 48x8 independent FMAs
//    so load latency pipelines. Weights are wave-uniform -> s_load on scalar pipe.
//  - ONE barrier; hs transposed [pos][HST] so dw reads are ds_read_b128, conflict-free.
//  - os fastest-varying in blockIdx -> the 8 blocks sharing an x-tile are adjacent -> L2 hits.
__global__ __launch_bounds__(256) void k_expdw(const float* __restrict__ xb,
                                               const float* __restrict__ wh,
                                               const float* __restrict__ wdw,
                                               float* __restrict__ h2s,
                                               int r0, int R, int tiles_y) {
    __shared__ float hs[256 * HST];   // 53.2 KB -> 3 blocks/CU
    int t = threadIdx.x;
    int tx = t & 15, ty = t >> 4;
    int blk = blockIdx.x;
    int os = blk % OSPLIT;            // fastest: consecutive blocks share the x tile
    int rest = blk / OSPLIT;
    int txi = rest % 19;
    int tyi = rest / 19;
    int r = r0 + tyi * 14 - 1 + ty;
    int c = txi * 14 - 1 + tx;
    int rcl = min(max(r, 0), 255), ccl = min(max(c, 0), 255);
    const float* xp = xb + rcl * 256 + ccl;
    const float* wb = wh + (os * CHB) * 64;   // CHB rows of 64 weights (wave-uniform)

    float acc[CHB];
#pragma unroll
    for (int o = 0; o < CHB; o++) acc[o] = 0.f;

    // streaming 1x1: 8 chunks of 8 input channels
    for (int ib = 0; ib < 8; ib++) {
        float xv[8];
#pragma unroll
        for (int j = 0; j < 8; j++) xv[j] = xp[(size_t)(ib * 8 + j) * HW];
#pragma unroll
        for (int o = 0; o < CHB; o++) {
            const float* wr = wb + o * 64 + ib * 8;
            float a = acc[o];
            a = fmaf(wr[0], xv[0], a);
            a = fmaf(wr[1], xv[1], a);
            a = fmaf(wr[2], xv[2], a);
            a = fmaf(wr[3], xv[3], a);
            a = fmaf(wr[4], xv[4], a);
            a = fmaf(wr[5], xv[5], a);
            a = fmaf(wr[6], xv[6], a);
            a = fmaf(wr[7], xv[7], a);
            acc[o] = a;
        }
    }

    // exchange hidden via LDS, transposed: hs[pos][ch]
#pragma unroll
    for (int c4 = 0; c4 < CHB / 4; c4++) {
        *(float4*)&hs[t * HST + c4 * 4] =
            make_float4(acc[c4 * 4 + 0], acc[c4 * 4 + 1], acc[c4 * 4 + 2], acc[c4 * 4 + 3]);
    }
    __syncthreads();

    bool interior = (ty >= 1 && ty <= 14 && tx >= 1 && tx <= 14 &&
                     r < r0 + R && r < 256 && c < 256);
    if (!interior) return;
    size_t SR = (size_t)R * 256;
    size_t base = (size_t)(r - r0) * 256 + c;
    const float* wd = wdw + (os * CHB) * 9;
#pragma unroll
    for (int c4 = 0; c4 < CHB / 4; c4++) {
        float4 a = make_float4(0.f, 0.f, 0.f, 0.f);
#pragma unroll
        for (int dr = -1; dr <= 1; dr++) {
            int rr = r + dr;
            if (rr < 0 || rr > 255) continue;
#pragma unroll
            for (int dc = -1; dc <= 1; dc++) {
                int cc2 = c + dc;
                if (cc2 < 0 || cc2 > 255) continue;
                float4 h = *(const float4*)&hs[((ty + dr) * 16 + tx + dc) * HST + c4 * 4];
                int kidx = (dr + 1) * 3 + (dc + 1);
                a.x = fmaf(wd[(c4 * 4 + 0) * 9 + kidx], h.x, a.x);
                a.y = fmaf(wd[(c4 * 4 + 1) * 9 + kidx], h.y, a.y);
                a.z = fmaf(wd[(c4 * 4 + 2) * 9 + kidx], h.z, a.z);
                a.w = fmaf(wd[(c4 * 4 + 3) * 9 + kidx], h.w, a.w);
            }
        }
        int o0 = os * CHB + c4 * 4;
        h2s[(size_t)(o0 + 0) * SR + base] = a.x;
        h2s[(size_t)(o0 + 1) * SR + base] = a.y;
        h2s[(size_t)(o0 + 2) * SR + base] = a.z;
        h2s[(size_t)(o0 + 3) * SR + base] = a.w;
    }
}

// ---------------- K2: fused per-patch: RMS+RoPE(q,k) -> circ-conv -> RMS -> *v -> project ------
__global__ __launch_bounds__(256, 2) void k_patch(const float* __restrict__ h2s,
                                                  const float* __restrict__ gq,
                                                  const float* __restrict__ gk,
                                                  const float* __restrict__ gn,
                                                  const float* __restrict__ wpt,
                                                  const float2* __restrict__ tab,
                                                  float* __restrict__ outb,
                                                  int r0, int R) {
    __shared__ float qs[C2 * CST];
    __shared__ float ks[C2 * CST];
    __shared__ float part[256], part2[256];
    __shared__ float sq[64], sk[64], scal[64];
    int t = threadIdx.x;
    int p = blockIdx.x;                 // (R/8)*32 patches
    int prs = p >> 5, pc = p & 31;
    size_t SR = (size_t)R * 256;
    size_t sb = (size_t)(prs * 8) * 256 + pc * 8;
    const float* qg = h2s + sb;
    const float* kg = h2s + 128 * SR + sb;
    const float* vg = h2s + 256 * SR + sb;

    // phase 1: load q,k patch to LDS
    for (int it = 0; it < 8; it++) {
        int l4 = it * 256 + t;
        int c = l4 >> 4, r4 = l4 & 15;
        int i = r4 >> 1, jq = r4 & 1;
        *(float4*)&qs[c * CST + i * 8 + jq * 4] = *(const float4*)(qg + (size_t)c * SR + i * 256 + jq * 4);
        *(float4*)&ks[c * CST + i * 8 + jq * 4] = *(const float4*)(kg + (size_t)c * SR + i * 256 + jq * 4);
    }
    __syncthreads();

    // phase 1b: per-position channel sums of q^2, k^2
    {
        int pos = t & 63, grp = t >> 6;
        float s1 = 0.f, s2 = 0.f;
        for (int c = grp * 32; c < grp * 32 + 32; c++) {
            float a = qs[c * CST + pos]; s1 = fmaf(a, a, s1);
            float e = ks[c * CST + pos]; s2 = fmaf(e, e, s2);
        }
        part[grp * 64 + pos] = s1;
        part2[grp * 64 + pos] = s2;
    }
    __syncthreads();
    if (t < 64) {
        sq[t] = rsqrtf((part[t] + part[64 + t] + part[128 + t] + part[192 + t]) * (1.f / 128.f) + EPS);
    } else if (t < 128) {
        int u = t - 64;
        sk[u] = rsqrtf((part2[u] + part2[64 + u] + part2[128 + u] + part2[192 + u]) * (1.f / 128.f) + EPS);
    }
    __syncthreads();

    // phase 1c: RMS-scale + RoPE in place (pairs 2m,2m+1)
    for (int u = 0; u < 16; u++) {
        int task = u * 256 + t;
        int m = task >> 6, pos = task & 63;
        int i = pos >> 3, j = pos & 7;
        float2 cs = (m < 32) ? tab[(r0 + prs * 8 + i) * 32 + m]
                             : tab[(pc * 8 + j) * 32 + (m - 32)];
        float sqp = sq[pos], skp = sk[pos];
        float q0 = qs[(2 * m) * CST + pos], q1 = qs[(2 * m + 1) * CST + pos];
        float y0 = gq[2 * m] * q0 * sqp, y1 = gq[2 * m + 1] * q1 * sqp;
        qs[(2 * m) * CST + pos] = y0 * cs.x - y1 * cs.y;
        qs[(2 * m + 1) * CST + pos] = y1 * cs.x + y0 * cs.y;
        float k0 = ks[(2 * m) * CST + pos], k1 = ks[(2 * m + 1) * CST + pos];
        float z0 = gk[2 * m] * k0 * skp, z1 = gk[2 * m + 1] * k1 * skp;
        ks[(2 * m) * CST + pos] = z0 * cs.x - z1 * cs.y;
        ks[(2 * m + 1) * CST + pos] = z1 * cs.x + z0 * cs.y;
    }
    __syncthreads();

    // phase 2: circular conv rows -> registers (task = (c, m), 4 per thread; UNROLLED so creg
    // stays in VGPRs, not scratch)
    float creg[4][8];
#pragma unroll
    for (int g4 = 0; g4 < 4; g4++) {
        int task = g4 * 256 + t;
        int c = task >> 3, m = task & 7;
        float o8[8] = {0, 0, 0, 0, 0, 0, 0, 0};
#pragma unroll
        for (int i = 0; i < 8; i++) {
            const float* qr = &qs[c * CST + i * 8];
            float4 qa = *(const float4*)qr, qb = *(const float4*)(qr + 4);
            float qq[8] = {qa.x, qa.y, qa.z, qa.w, qb.x, qb.y, qb.z, qb.w};
            int kr = (m - i) & 7;
            const float* krp = &ks[c * CST + kr * 8];
            float4 ka = *(const float4*)krp, kb2 = *(const float4*)(krp + 4);
            float kk[8] = {ka.x, ka.y, ka.z, ka.w, kb2.x, kb2.y, kb2.z, kb2.w};
#pragma unroll
            for (int n = 0; n < 8; n++)
#pragma unroll
                for (int j = 0; j < 8; j++)
                    o8[n] = fmaf(qq[j], kk[(n - j) & 7], o8[n]);
        }
#pragma unroll
        for (int n = 0; n < 8; n++) creg[g4][n] = o8[n];
    }
    __syncthreads();

    // phase 3: store corr over qs
#pragma unroll
    for (int g4 = 0; g4 < 4; g4++) {
        int task = g4 * 256 + t;
        int c = task >> 3, m = task & 7;
        *(float4*)&qs[c * CST + m * 8] =
            make_float4(creg[g4][0], creg[g4][1], creg[g4][2], creg[g4][3]);
        *(float4*)&qs[c * CST + m * 8 + 4] =
            make_float4(creg[g4][4], creg[g4][5], creg[g4][6], creg[g4][7]);
    }
    __syncthreads();

    // phase 4: per-position sum of corr^2 over channels
    {
        int pos = t & 63, q4 = t >> 6;
        float ssum = 0.f;
        for (int c = q4 * 32; c < q4 * 32 + 32; c++) {
            float v = qs[c * CST + pos];
            ssum = fmaf(v, v, ssum);
        }
        part[q4 * 64 + pos] = ssum;
    }
    __syncthreads();
    if (t < 64) {
        float s = part[t] + part[64 + t] + part[128 + t] + part[192 + t];
        scal[t] = rsqrtf(s * (1.0f / 128.f) + EPS);
    }
    __syncthreads();

    // phase 5: tmod in place: qs[c][pos] = corr*scal[pos]*gn[c]*v[c][pos]
    for (int it = 0; it < 8; it++) {
        int l4 = it * 256 + t;
        int c = l4 >> 4, r4 = l4 & 15;
        int i = r4 >> 1, jq = r4 & 1;
        float4 vv = *(const float4*)(vg + (size_t)c * SR + i * 256 + jq * 4);
        float4 sc4 = *(const float4*)&scal[r4 * 4];
        float g = gn[c];
        float4 cu = *(float4*)&qs[c * CST + r4 * 4];
        cu.x = cu.x * sc4.x * g * vv.x;
        cu.y = cu.y * sc4.y * g * vv.y;
        cu.z = cu.z * sc4.z * g * vv.z;
        cu.w = cu.w * sc4.w * g * vv.w;
        *(float4*)&qs[c * CST + r4 * 4] = cu;
    }
    __syncthreads();

    // phase 6: project 128->64, stage to ks as out_s[pos*CST + o]
    {
        int o = t & 63, pg = t >> 6;
        float acc[16];
#pragma unroll
        for (int u = 0; u < 16; u++) acc[u] = 0.f;
        for (int c = 0; c < C2; c++) {
            float w = wpt[c * 64 + o];
            const float* tp = &qs[c * CST + pg * 16];
#pragma unroll
            for (int u4 = 0; u4 < 4; u4++) {
                float4 tv = *(const float4*)(tp + u4 * 4);
                acc[u4 * 4 + 0] = fmaf(w, tv.x, acc[u4 * 4 + 0]);
                acc[u4 * 4 + 1] = fmaf(w, tv.y, acc[u4 * 4 + 1]);
                acc[u4 * 4 + 2] = fmaf(w, tv.z, acc[u4 * 4 + 2]);
                acc[u4 * 4 + 3] = fmaf(w, tv.w, acc[u4 * 4 + 3]);
            }
        }
#pragma unroll
        for (int u = 0; u < 16; u++) ks[(pg * 16 + u) * CST + o] = acc[u];
    }
    __syncthreads();

    // phase 7: coalesced out write
    float* og = outb + (size_t)r0 * 256 + sb;
    for (int it = 0; it < 4; it++) {
        int l4 = it * 256 + t;
        int o = l4 >> 4, r4 = l4 & 15;
        int i = r4 >> 1, jq = r4 & 1;
        int p0 = i * 8 + jq * 4;
        float4 vv = make_float4(ks[(p0 + 0) * CST + o], ks[(p0 + 1) * CST + o],
                                ks[(p0 + 2) * CST + o], ks[(p0 + 3) * CST + o]);
        *(float4*)(og + (size_t)o * HW + i * 256 + jq * 4) = vv;
    }
}

extern "C" void kernel_launch(void* const* d_in, const int* in_sizes, int n_in,
                              void* d_out, int out_size, void* d_ws, size_t ws_size,
                              hipStream_t stream) {
    const float* x   = (const float*)d_in[0];
    const float* wh  = (const float*)d_in[1];
    const float* wdw = (const float*)d_in[2];
    const float* wp  = (const float*)d_in[3];
    const float* gn  = (const float*)d_in[4];
    const float* gq  = (const float*)d_in[5];
    const float* gk  = (const float*)d_in[6];
    float* out = (float*)d_out;

    // ws layout (floats): tab[16384] | wpt[8192] | h2s[384 * R * 256]
    size_t avail = ws_size / 4;
    if (avail < (size_t)24576 + (size_t)C6 * 8 * 256) return;  // need at least R=8
    size_t rows_cap = (avail - 24576) / ((size_t)C6 * 256);
    int R = (rows_cap >= 256) ? 256 : (int)(rows_cap & ~(size_t)7);

    float* ws = (float*)d_ws;
    float2* tab = (float2*)ws;
    float* wpt  = ws + 16384;
    float* h2s  = ws + 24576;

    k_tab<<<32, 256, 0, stream>>>(tab);
    k_wt<<<32, 256, 0, stream>>>(wp, wpt);
    for (int b = 0; b < BB; b++) {
        const float* xb = x + (size_t)b * Cc * HW;
        float* outb = out + (size_t)b * Cc * HW;
        for (int r0 = 0; r0 < 256; r0 += R) {
            int Rc = (256 - r0 < R) ? (256 - r0) : R;
            int tiles_y = (Rc + 13) / 14;
            k_expdw<<<19 * tiles_y * OSPLIT, 256, 0, stream>>>(xb, wh, wdw, h2s, r0, Rc, tiles_y);
            k_patch<<<(Rc / 8) * 32, 256, 0, stream>>>(h2s, gq, gk, gn, wpt, tab, outb, r0, Rc);
        }
    }
}

// Round 7
// 1073.918 us; speedup vs baseline: 1.8331x; 1.2803x over previous
//
#include <hip/hip_runtime.h>
#include <math.h>

#define BB 4
#define Cc 64
#define C2 128
#define C6 384
#define HW 65536
#define EPS 1e-6f
#define CST 68      // padded LDS channel stride (patch kernel)
#define OSPLIT 12   // output-channel split across blocks
#define CHB 32      // channels per block = 384/OSPLIT
#define HCH 16      // channels per dw-exchange chunk (2 chunks)
#define HPAD 20     // hs row stride in floats: 8 distinct bank-quad starts -> conflict-free b128
#define TW 16       // tile width (cols), interior 14
#define TH 32       // tile height (rows), interior 30

// ---------------- K0: RoPE table: tab[r*32+m] = (cos(r*inv[m]), sin(r*inv[m])) ----------------
__global__ void k_tab(float2* __restrict__ tab) {
    int idx = blockIdx.x * 256 + threadIdx.x;   // 8192 entries
    if (idx >= 256 * 32) return;
    int r = idx >> 5, m = idx & 31;
    float inv = expf(-((2.0f * (float)m) / 64.0f) * logf(10000.0f));
    float s, c;
    sincosf((float)r * inv, &s, &c);
    tab[idx] = make_float2(c, s);
}

// ---------------- K0b: transpose w_proj (64x128) -> wpt (128x64) ----------------
__global__ void k_wt(const float* __restrict__ wp, float* __restrict__ wpt) {
    int t = blockIdx.x * 256 + threadIdx.x;
    if (t >= 64 * 128) return;
    int o = t >> 7, cc = t & 127;
    wpt[cc * 64 + o] = wp[o * 128 + cc];
}

// ---------------- K1: fused 1x1 expand + depthwise 3x3 ----------------
// R6 post-mortem: R0 (reload, VALU 30%, occ 63%) and R6 (stream-once, VALU 58%, occ 29%)
// both land at ~240us -> the invariant limiter is the uniform weight-fetch chain:
// 1 s_load_dwordx8 per 8 FMAs with SGPR file maxed (112) -> scalar-latency-bound.
// R7: 2 positions per thread (rows ty0 and ty0+16 of a 16x32 tile) -> each weight feeds
// 16 FMAs; CHB 48->32 keeps acc[2][32]+xv[16] ~100 VGPR (no spill). dw exchange chunked
// (2 x 16ch) through 40KB LDS (stride 20 floats -> conflict-free b128) -> ~4 blocks/CU
// so the 4 barriers hide behind TLP (R5 lesson).
__global__ __launch_bounds__(256) void k_expdw(const float* __restrict__ xb,
                                               const float* __restrict__ wh,
                                               const float* __restrict__ wdw,
                                               float* __restrict__ h2s,
                                               int r0, int R, int tiles_y) {
    __shared__ float hs[TW * TH * HPAD];   // 512*20*4B = 40KB
    int t = threadIdx.x;
    int tx = t & 15, ty0 = t >> 4;         // ty0 in [0,16)
    int blk = blockIdx.x;
    int os = blk % OSPLIT;                 // fastest: 12 adjacent blocks share the x tile (L2)
    int rest = blk / OSPLIT;
    int txi = rest % 19;
    int tyi = rest / 19;
    int c = txi * 14 - 1 + tx;
    int rA = r0 + tyi * 30 - 1 + ty0;      // position A: tile row ty0
    int rB = rA + 16;                      // position B: tile row ty0+16
    int ccl = min(max(c, 0), 255);
    int rclA = min(max(rA, 0), 255), rclB = min(max(rB, 0), 255);
    const float* xpA = xb + rclA * 256 + ccl;
    const float* xpB = xb + rclB * 256 + ccl;
    const float* wb = wh + (os * CHB) * 64;   // wave-uniform -> s_load

    float accA[CHB], accB[CHB];
#pragma unroll
    for (int o = 0; o < CHB; o++) { accA[o] = 0.f; accB[o] = 0.f; }

    // streaming 1x1: 8 chunks of 8 input channels; each weight feeds 2 positions
    for (int ib = 0; ib < 8; ib++) {
        float xa[8], xbv[8];
#pragma unroll
        for (int j = 0; j < 8; j++) {
            xa[j]  = xpA[(size_t)(ib * 8 + j) * HW];
            xbv[j] = xpB[(size_t)(ib * 8 + j) * HW];
        }
#pragma unroll
        for (int o = 0; o < CHB; o++) {
            const float* wr = wb + o * 64 + ib * 8;
            float4 w0 = *(const float4*)wr;
            float4 w1 = *(const float4*)(wr + 4);
            float a = accA[o], b = accB[o];
            a = fmaf(w0.x, xa[0], a);  b = fmaf(w0.x, xbv[0], b);
            a = fmaf(w0.y, xa[1], a);  b = fmaf(w0.y, xbv[1], b);
            a = fmaf(w0.z, xa[2], a);  b = fmaf(w0.z, xbv[2], b);
            a = fmaf(w0.w, xa[3], a);  b = fmaf(w0.w, xbv[3], b);
            a = fmaf(w1.x, xa[4], a);  b = fmaf(w1.x, xbv[4], b);
            a = fmaf(w1.y, xa[5], a);  b = fmaf(w1.y, xbv[5], b);
            a = fmaf(w1.z, xa[6], a);  b = fmaf(w1.z, xbv[6], b);
            a = fmaf(w1.w, xa[7], a);  b = fmaf(w1.w, xbv[7], b);
            accA[o] = a; accB[o] = b;
        }
    }

    // dw exchange + conv, chunked in 16-channel halves to keep LDS at 40KB
    bool colInt = (tx >= 1 && tx <= 14 && c < 256);
    bool intA = colInt && (ty0 >= 1) && (rA < r0 + R) && (rA < 256);
    bool intB = colInt && (ty0 <= 14) && (rB < r0 + R) && (rB < 256);
    int pA = ty0 * TW + tx, pB = pA + 256;
    size_t SR = (size_t)R * 256;
    const float* wd = wdw + (os * CHB) * 9;

#pragma unroll
    for (int cc2 = 0; cc2 < 2; cc2++) {
        // write this chunk's 16 channels for both positions
#pragma unroll
        for (int q = 0; q < 4; q++) {
            int ch = cc2 * HCH + q * 4;
            *(float4*)&hs[pA * HPAD + q * 4] =
                make_float4(accA[ch + 0], accA[ch + 1], accA[ch + 2], accA[ch + 3]);
            *(float4*)&hs[pB * HPAD + q * 4] =
                make_float4(accB[ch + 0], accB[ch + 1], accB[ch + 2], accB[ch + 3]);
        }
        __syncthreads();
        // depthwise 3x3 for interior positions
#pragma unroll
        for (int side = 0; side < 2; side++) {
            bool act = side ? intB : intA;
            int p = side ? pB : pA;
            int r = side ? rB : rA;
            if (act) {
                size_t base = (size_t)(r - r0) * 256 + c;
#pragma unroll
                for (int q = 0; q < 4; q++) {
                    int ch = cc2 * HCH + q * 4;
                    float4 a = make_float4(0.f, 0.f, 0.f, 0.f);
#pragma unroll
                    for (int dr = -1; dr <= 1; dr++) {
                        int rr = r + dr;
                        if (rr < 0 || rr > 255) continue;
#pragma unroll
                        for (int dc = -1; dc <= 1; dc++) {
                            int cn = c + dc;
                            if (cn < 0 || cn > 255) continue;
                            float4 h = *(const float4*)&hs[(p + dr * TW + dc) * HPAD + q * 4];
                            int kidx = (dr + 1) * 3 + (dc + 1);
                            a.x = fmaf(wd[(ch + 0) * 9 + kidx], h.x, a.x);
                            a.y = fmaf(wd[(ch + 1) * 9 + kidx], h.y, a.y);
                            a.z = fmaf(wd[(ch + 2) * 9 + kidx], h.z, a.z);
                            a.w = fmaf(wd[(ch + 3) * 9 + kidx], h.w, a.w);
                        }
                    }
                    int o0 = os * CHB + ch;
                    h2s[(size_t)(o0 + 0) * SR + base] = a.x;
                    h2s[(size_t)(o0 + 1) * SR + base] = a.y;
                    h2s[(size_t)(o0 + 2) * SR + base] = a.z;
                    h2s[(size_t)(o0 + 3) * SR + base] = a.w;
                }
            }
        }
        __syncthreads();
    }
}

// ---------------- K2: fused per-patch: RMS+RoPE(q,k) -> circ-conv -> RMS -> *v -> project ------
__global__ __launch_bounds__(256, 2) void k_patch(const float* __restrict__ h2s,
                                                  const float* __restrict__ gq,
                                                  const float* __restrict__ gk,
                                                  const float* __restrict__ gn,
                                                  const float* __restrict__ wpt,
                                                  const float2* __restrict__ tab,
                                                  float* __restrict__ outb,
                                                  int r0, int R) {
    __shared__ float qs[C2 * CST];
    __shared__ float ks[C2 * CST];
    __shared__ float part[256], part2[256];
    __shared__ float sq[64], sk[64], scal[64];
    int t = threadIdx.x;
    int p = blockIdx.x;                 // (R/8)*32 patches
    int prs = p >> 5, pc = p & 31;
    size_t SR = (size_t)R * 256;
    size_t sb = (size_t)(prs * 8) * 256 + pc * 8;
    const float* qg = h2s + sb;
    const float* kg = h2s + 128 * SR + sb;
    const float* vg = h2s + 256 * SR + sb;

    // phase 1: load q,k patch to LDS
    for (int it = 0; it < 8; it++) {
        int l4 = it * 256 + t;
        int c = l4 >> 4, r4 = l4 & 15;
        int i = r4 >> 1, jq = r4 & 1;
        *(float4*)&qs[c * CST + i * 8 + jq * 4] = *(const float4*)(qg + (size_t)c * SR + i * 256 + jq * 4);
        *(float4*)&ks[c * CST + i * 8 + jq * 4] = *(const float4*)(kg + (size_t)c * SR + i * 256 + jq * 4);
    }
    __syncthreads();

    // phase 1b: per-position channel sums of q^2, k^2
    {
        int pos = t & 63, grp = t >> 6;
        float s1 = 0.f, s2 = 0.f;
        for (int c = grp * 32; c < grp * 32 + 32; c++) {
            float a = qs[c * CST + pos]; s1 = fmaf(a, a, s1);
            float e = ks[c * CST + pos]; s2 = fmaf(e, e, s2);
        }
        part[grp * 64 + pos] = s1;
        part2[grp * 64 + pos] = s2;
    }
    __syncthreads();
    if (t < 64) {
        sq[t] = rsqrtf((part[t] + part[64 + t] + part[128 + t] + part[192 + t]) * (1.f / 128.f) + EPS);
    } else if (t < 128) {
        int u = t - 64;
        sk[u] = rsqrtf((part2[u] + part2[64 + u] + part2[128 + u] + part2[192 + u]) * (1.f / 128.f) + EPS);
    }
    __syncthreads();

    // phase 1c: RMS-scale + RoPE in place (pairs 2m,2m+1)
    for (int u = 0; u < 16; u++) {
        int task = u * 256 + t;
        int m = task >> 6, pos = task & 63;
        int i = pos >> 3, j = pos & 7;
        float2 cs = (m < 32) ? tab[(r0 + prs * 8 + i) * 32 + m]
                             : tab[(pc * 8 + j) * 32 + (m - 32)];
        float sqp = sq[pos], skp = sk[pos];
        float q0 = qs[(2 * m) * CST + pos], q1 = qs[(2 * m + 1) * CST + pos];
        float y0 = gq[2 * m] * q0 * sqp, y1 = gq[2 * m + 1] * q1 * sqp;
        qs[(2 * m) * CST + pos] = y0 * cs.x - y1 * cs.y;
        qs[(2 * m + 1) * CST + pos] = y1 * cs.x + y0 * cs.y;
        float k0 = ks[(2 * m) * CST + pos], k1 = ks[(2 * m + 1) * CST + pos];
        float z0 = gk[2 * m] * k0 * skp, z1 = gk[2 * m + 1] * k1 * skp;
        ks[(2 * m) * CST + pos] = z0 * cs.x - z1 * cs.y;
        ks[(2 * m + 1) * CST + pos] = z1 * cs.x + z0 * cs.y;
    }
    __syncthreads();

    // phase 2: circular conv rows -> registers (task = (c, m), 4 per thread; UNROLLED so creg
    // stays in VGPRs, not scratch)
    float creg[4][8];
#pragma unroll
    for (int g4 = 0; g4 < 4; g4++) {
        int task = g4 * 256 + t;
        int c = task >> 3, m = task & 7;
        float o8[8] = {0, 0, 0, 0, 0, 0, 0, 0};
#pragma unroll
        for (int i = 0; i < 8; i++) {
            const float* qr = &qs[c * CST + i * 8];
            float4 qa = *(const float4*)qr, qb = *(const float4*)(qr + 4);
            float qq[8] = {qa.x, qa.y, qa.z, qa.w, qb.x, qb.y, qb.z, qb.w};
            int kr = (m - i) & 7;
            const float* krp = &ks[c * CST + kr * 8];
            float4 ka = *(const float4*)krp, kb2 = *(const float4*)(krp + 4);
            float kk[8] = {ka.x, ka.y, ka.z, ka.w, kb2.x, kb2.y, kb2.z, kb2.w};
#pragma unroll
            for (int n = 0; n < 8; n++)
#pragma unroll
                for (int j = 0; j < 8; j++)
                    o8[n] = fmaf(qq[j], kk[(n - j) & 7], o8[n]);
        }
#pragma unroll
        for (int n = 0; n < 8; n++) creg[g4][n] = o8[n];
    }
    __syncthreads();

    // phase 3: store corr over qs
#pragma unroll
    for (int g4 = 0; g4 < 4; g4++) {
        int task = g4 * 256 + t;
        int c = task >> 3, m = task & 7;
        *(float4*)&qs[c * CST + m * 8] =
            make_float4(creg[g4][0], creg[g4][1], creg[g4][2], creg[g4][3]);
        *(float4*)&qs[c * CST + m * 8 + 4] =
            make_float4(creg[g4][4], creg[g4][5], creg[g4][6], creg[g4][7]);
    }
    __syncthreads();

    // phase 4: per-position sum of corr^2 over channels
    {
        int pos = t & 63, q4 = t >> 6;
        float ssum = 0.f;
        for (int c = q4 * 32; c < q4 * 32 + 32; c++) {
            float v = qs[c * CST + pos];
            ssum = fmaf(v, v, ssum);
        }
        part[q4 * 64 + pos] = ssum;
    }
    __syncthreads();
    if (t < 64) {
        float s = part[t] + part[64 + t] + part[128 + t] + part[192 + t];
        scal[t] = rsqrtf(s * (1.0f / 128.f) + EPS);
    }
    __syncthreads();

    // phase 5: tmod in place: qs[c][pos] = corr*scal[pos]*gn[c]*v[c][pos]
    for (int it = 0; it < 8; it++) {
        int l4 = it * 256 + t;
        int c = l4 >> 4, r4 = l4 & 15;
        int i = r4 >> 1, jq = r4 & 1;
        float4 vv = *(const float4*)(vg + (size_t)c * SR + i * 256 + jq * 4);
        float4 sc4 = *(const float4*)&scal[r4 * 4];
        float g = gn[c];
        float4 cu = *(float4*)&qs[c * CST + r4 * 4];
        cu.x = cu.x * sc4.x * g * vv.x;
        cu.y = cu.y * sc4.y * g * vv.y;
        cu.z = cu.z * sc4.z * g * vv.z;
        cu.w = cu.w * sc4.w * g * vv.w;
        *(float4*)&qs[c * CST + r4 * 4] = cu;
    }
    __syncthreads();

    // phase 6: project 128->64, stage to ks as out_s[pos*CST + o]
    {
        int o = t & 63, pg = t >> 6;
        float acc[16];
#pragma unroll
        for (int u = 0; u < 16; u++) acc[u] = 0.f;
        for (int c = 0; c < C2; c++) {
            float w = wpt[c * 64 + o];
            const float* tp = &qs[c * CST + pg * 16];
#pragma unroll
            for (int u4 = 0; u4 < 4; u4++) {
                float4 tv = *(const float4*)(tp + u4 * 4);
                acc[u4 * 4 + 0] = fmaf(w, tv.x, acc[u4 * 4 + 0]);
                acc[u4 * 4 + 1] = fmaf(w, tv.y, acc[u4 * 4 + 1]);
                acc[u4 * 4 + 2] = fmaf(w, tv.z, acc[u4 * 4 + 2]);
                acc[u4 * 4 + 3] = fmaf(w, tv.w, acc[u4 * 4 + 3]);
            }
        }
#pragma unroll
        for (int u = 0; u < 16; u++) ks[(pg * 16 + u) * CST + o] = acc[u];
    }
    __syncthreads();

    // phase 7: coalesced out write
    float* og = outb + (size_t)r0 * 256 + sb;
    for (int it = 0; it < 4; it++) {
        int l4 = it * 256 + t;
        int o = l4 >> 4, r4 = l4 & 15;
        int i = r4 >> 1, jq = r4 & 1;
        int p0 = i * 8 + jq * 4;
        float4 vv = make_float4(ks[(p0 + 0) * CST + o], ks[(p0 + 1) * CST + o],
                                ks[(p0 + 2) * CST + o], ks[(p0 + 3) * CST + o]);
        *(float4*)(og + (size_t)o * HW + i * 256 + jq * 4) = vv;
    }
}

extern "C" void kernel_launch(void* const* d_in, const int* in_sizes, int n_in,
                              void* d_out, int out_size, void* d_ws, size_t ws_size,
                              hipStream_t stream) {
    const float* x   = (const float*)d_in[0];
    const float* wh  = (const float*)d_in[1];
    const float* wdw = (const float*)d_in[2];
    const float* wp  = (const float*)d_in[3];
    const float* gn  = (const float*)d_in[4];
    const float* gq  = (const float*)d_in[5];
    const float* gk  = (const float*)d_in[6];
    float* out = (float*)d_out;

    // ws layout (floats): tab[16384] | wpt[8192] | h2s[384 * R * 256]
    size_t avail = ws_size / 4;
    if (avail < (size_t)24576 + (size_t)C6 * 8 * 256) return;  // need at least R=8
    size_t rows_cap = (avail - 24576) / ((size_t)C6 * 256);
    int R = (rows_cap >= 256) ? 256 : (int)(rows_cap & ~(size_t)7);

    float* ws = (float*)d_ws;
    float2* tab = (float2*)ws;
    float* wpt  = ws + 16384;
    float* h2s  = ws + 24576;

    k_tab<<<32, 256, 0, stream>>>(tab);
    k_wt<<<32, 256, 0, stream>>>(wp, wpt);
    for (int b = 0; b < BB; b++) {
        const float* xb = x + (size_t)b * Cc * HW;
        float* outb = out + (size_t)b * Cc * HW;
        for (int r0 = 0; r0 < 256; r0 += R) {
            int Rc = (256 - r0 < R) ? (256 - r0) : R;
            int tiles_y = (Rc + 29) / 30;
            k_expdw<<<19 * tiles_y * OSPLIT, 256, 0, stream>>>(xb, wh, wdw, h2s, r0, Rc, tiles_y);
            k_patch<<<(Rc / 8) * 32, 256, 0, stream>>>(h2s, gq, gk, gn, wpt, tab, outb, r0, Rc);
        }
    }
}

// Round 9
// 1002.130 us; speedup vs baseline: 1.9644x; 1.0716x over previous
//
#include <hip/hip_runtime.h>
#include <math.h>

#define BB 4
#define Cc 64
#define C2 128
#define C6 384
#define HW 65536
#define EPS 1e-6f
#define CST 68      // padded LDS channel stride (patch kernel)
#define OSPLIT 12   // output-channel split across blocks
#define CHB 32      // channels per block = 384/OSPLIT
#define HCH 16      // channels per dw-exchange chunk (2 chunks)
#define HPAD 20     // hs row stride in floats: 8 distinct bank-quad starts -> conflict-free b128
#define TW 16       // tile width (cols), interior 14
#define TH 32       // tile height (rows), interior 30

// ---------------- K0: RoPE table: tab[r*32+m] = (cos(r*inv[m]), sin(r*inv[m])) ----------------
__global__ void k_tab(float2* __restrict__ tab) {
    int idx = blockIdx.x * 256 + threadIdx.x;   // 8192 entries
    if (idx >= 256 * 32) return;
    int r = idx >> 5, m = idx & 31;
    float inv = expf(-((2.0f * (float)m) / 64.0f) * logf(10000.0f));
    float s, c;
    sincosf((float)r * inv, &s, &c);
    tab[idx] = make_float2(c, s);
}

// ---------------- K0b: transpose w_proj (64x128) -> wpt (128x64) ----------------
__global__ void k_wt(const float* __restrict__ wp, float* __restrict__ wpt) {
    int t = blockIdx.x * 256 + threadIdx.x;
    if (t >= 64 * 128) return;
    int o = t >> 7, cc = t & 127;
    wpt[cc * 64 + o] = wp[o * 128 + cc];
}

// ---------------- K1: fused 1x1 expand + depthwise 3x3 ----------------
// R7 (166us/dispatch, VALU 47%): limiter is the wave-uniform weight stream — 1
// s_load_dwordx8 per 16 FMAs, SGPR file maxed -> scalar-latency chain. R8: stage wh-slice
// (8KB) + wdw-slice (1.2KB) in LDS; inner loop reads weights via uniform ds_read_b128.
// R8 post-mortem: wdl stage was `if (t < 288)` with ONE entry/thread but only 256 threads
// -> kidx=8 tap row never written (uninitialized LDS) -> absmax 5.65. R9: grid-stride
// staging loop covers all 288 entries. Design otherwise identical to R8.
__global__ __launch_bounds__(256) void k_expdw(const float* __restrict__ xb,
                                               const float* __restrict__ wh,
                                               const float* __restrict__ wdw,
                                               float* __restrict__ h2s,
                                               int r0, int R, int tiles_y) {
    __shared__ float hs[TW * TH * HPAD];   // 512*20*4B = 40KB
    __shared__ float wl[CHB * 64];         // 8KB: wl[o*64+i], 1x1 weights for this os-slice
    __shared__ float wdl[9 * CHB];         // 1.2KB: wdl[k*CHB+ch], dw taps transposed
    int t = threadIdx.x;
    int tx = t & 15, ty0 = t >> 4;         // ty0 in [0,16)
    int blk = blockIdx.x;
    int os = blk % OSPLIT;                 // fastest: 12 adjacent blocks share the x tile (L2)
    int rest = blk / OSPLIT;
    int txi = rest % 19;
    int tyi = rest / 19;
    int c = txi * 14 - 1 + tx;
    int rA = r0 + tyi * 30 - 1 + ty0;      // position A: tile row ty0
    int rB = rA + 16;                      // position B: tile row ty0+16
    int ccl = min(max(c, 0), 255);
    int rclA = min(max(rA, 0), 255), rclB = min(max(rB, 0), 255);
    const float* xpA = xb + rclA * 256 + ccl;
    const float* xpB = xb + rclB * 256 + ccl;

    // stage weights to LDS (one time per block)
    {
        const float* wsrc = wh + (os * CHB) * 64;          // 2048 floats
#pragma unroll
        for (int u = 0; u < 8; u++) wl[u * 256 + t] = wsrc[u * 256 + t];
        for (int u = t; u < 9 * CHB; u += 256) {           // 288 floats, transpose to [k][ch]
            int k = u >> 5, ch = u & 31;
            wdl[u] = wdw[(os * CHB + ch) * 9 + k];         // wdl[k*CHB+ch], u == k*32+ch
        }
    }
    __syncthreads();

    float accA[CHB], accB[CHB];
#pragma unroll
    for (int o = 0; o < CHB; o++) { accA[o] = 0.f; accB[o] = 0.f; }

    // streaming 1x1: 8 chunks of 8 input channels; weights broadcast from LDS
    for (int ib = 0; ib < 8; ib++) {
        float xa[8], xbv[8];
#pragma unroll
        for (int j = 0; j < 8; j++) {
            xa[j]  = xpA[(size_t)(ib * 8 + j) * HW];
            xbv[j] = xpB[(size_t)(ib * 8 + j) * HW];
        }
#pragma unroll
        for (int o = 0; o < CHB; o++) {
            const float* wr = &wl[o * 64 + ib * 8];
            float4 w0 = *(const float4*)wr;        // ds_read_b128, uniform -> broadcast
            float4 w1 = *(const float4*)(wr + 4);
            float a = accA[o], b = accB[o];
            a = fmaf(w0.x, xa[0], a);  b = fmaf(w0.x, xbv[0], b);
            a = fmaf(w0.y, xa[1], a);  b = fmaf(w0.y, xbv[1], b);
            a = fmaf(w0.z, xa[2], a);  b = fmaf(w0.z, xbv[2], b);
            a = fmaf(w0.w, xa[3], a);  b = fmaf(w0.w, xbv[3], b);
            a = fmaf(w1.x, xa[4], a);  b = fmaf(w1.x, xbv[4], b);
            a = fmaf(w1.y, xa[5], a);  b = fmaf(w1.y, xbv[5], b);
            a = fmaf(w1.z, xa[6], a);  b = fmaf(w1.z, xbv[6], b);
            a = fmaf(w1.w, xa[7], a);  b = fmaf(w1.w, xbv[7], b);
            accA[o] = a; accB[o] = b;
        }
    }

    // dw exchange + conv, chunked in 16-channel halves to keep LDS bounded
    bool colInt = (tx >= 1 && tx <= 14 && c < 256);
    bool intA = colInt && (ty0 >= 1) && (rA < r0 + R) && (rA < 256);
    bool intB = colInt && (ty0 <= 14) && (rB < r0 + R) && (rB < 256);
    int pA = ty0 * TW + tx, pB = pA + 256;
    size_t SR = (size_t)R * 256;

#pragma unroll
    for (int cc2 = 0; cc2 < 2; cc2++) {
        // write this chunk's 16 channels for both positions
#pragma unroll
        for (int q = 0; q < 4; q++) {
            int ch = cc2 * HCH + q * 4;
            *(float4*)&hs[pA * HPAD + q * 4] =
                make_float4(accA[ch + 0], accA[ch + 1], accA[ch + 2], accA[ch + 3]);
            *(float4*)&hs[pB * HPAD + q * 4] =
                make_float4(accB[ch + 0], accB[ch + 1], accB[ch + 2], accB[ch + 3]);
        }
        __syncthreads();
        // depthwise 3x3 for interior positions (taps broadcast from LDS)
#pragma unroll
        for (int side = 0; side < 2; side++) {
            bool act = side ? intB : intA;
            int p = side ? pB : pA;
            int r = side ? rB : rA;
            if (act) {
                size_t base = (size_t)(r - r0) * 256 + c;
#pragma unroll
                for (int q = 0; q < 4; q++) {
                    int ch = cc2 * HCH + q * 4;
                    float4 a = make_float4(0.f, 0.f, 0.f, 0.f);
#pragma unroll
                    for (int dr = -1; dr <= 1; dr++) {
                        int rr = r + dr;
                        if (rr < 0 || rr > 255) continue;
#pragma unroll
                        for (int dc = -1; dc <= 1; dc++) {
                            int cn = c + dc;
                            if (cn < 0 || cn > 255) continue;
                            float4 h = *(const float4*)&hs[(p + dr * TW + dc) * HPAD + q * 4];
                            int kidx = (dr + 1) * 3 + (dc + 1);
                            float4 wt = *(const float4*)&wdl[kidx * CHB + ch];  // uniform b128
                            a.x = fmaf(wt.x, h.x, a.x);
                            a.y = fmaf(wt.y, h.y, a.y);
                            a.z = fmaf(wt.z, h.z, a.z);
                            a.w = fmaf(wt.w, h.w, a.w);
                        }
                    }
                    int o0 = os * CHB + ch;
                    h2s[(size_t)(o0 + 0) * SR + base] = a.x;
                    h2s[(size_t)(o0 + 1) * SR + base] = a.y;
                    h2s[(size_t)(o0 + 2) * SR + base] = a.z;
                    h2s[(size_t)(o0 + 3) * SR + base] = a.w;
                }
            }
        }
        __syncthreads();
    }
}

// ---------------- K2: fused per-patch: RMS+RoPE(q,k) -> circ-conv -> RMS -> *v -> project ------
__global__ __launch_bounds__(256, 2) void k_patch(const float* __restrict__ h2s,
                                                  const float* __restrict__ gq,
                                                  const float* __restrict__ gk,
                                                  const float* __restrict__ gn,
                                                  const float* __restrict__ wpt,
                                                  const float2* __restrict__ tab,
                                                  float* __restrict__ outb,
                                                  int r0, int R) {
    __shared__ float qs[C2 * CST];
    __shared__ float ks[C2 * CST];
    __shared__ float part[256], part2[256];
    __shared__ float sq[64], sk[64], scal[64];
    int t = threadIdx.x;
    int p = blockIdx.x;                 // (R/8)*32 patches
    int prs = p >> 5, pc = p & 31;
    size_t SR = (size_t)R * 256;
    size_t sb = (size_t)(prs * 8) * 256 + pc * 8;
    const float* qg = h2s + sb;
    const float* kg = h2s + 128 * SR + sb;
    const float* vg = h2s + 256 * SR + sb;

    // phase 1: load q,k patch to LDS
    for (int it = 0; it < 8; it++) {
        int l4 = it * 256 + t;
        int c = l4 >> 4, r4 = l4 & 15;
        int i = r4 >> 1, jq = r4 & 1;
        *(float4*)&qs[c * CST + i * 8 + jq * 4] = *(const float4*)(qg + (size_t)c * SR + i * 256 + jq * 4);
        *(float4*)&ks[c * CST + i * 8 + jq * 4] = *(const float4*)(kg + (size_t)c * SR + i * 256 + jq * 4);
    }
    __syncthreads();

    // phase 1b: per-position channel sums of q^2, k^2
    {
        int pos = t & 63, grp = t >> 6;
        float s1 = 0.f, s2 = 0.f;
        for (int c = grp * 32; c < grp * 32 + 32; c++) {
            float a = qs[c * CST + pos]; s1 = fmaf(a, a, s1);
            float e = ks[c * CST + pos]; s2 = fmaf(e, e, s2);
        }
        part[grp * 64 + pos] = s1;
        part2[grp * 64 + pos] = s2;
    }
    __syncthreads();
    if (t < 64) {
        sq[t] = rsqrtf((part[t] + part[64 + t] + part[128 + t] + part[192 + t]) * (1.f / 128.f) + EPS);
    } else if (t < 128) {
        int u = t - 64;
        sk[u] = rsqrtf((part2[u] + part2[64 + u] + part2[128 + u] + part2[192 + u]) * (1.f / 128.f) + EPS);
    }
    __syncthreads();

    // phase 1c: RMS-scale + RoPE in place (pairs 2m,2m+1)
    for (int u = 0; u < 16; u++) {
        int task = u * 256 + t;
        int m = task >> 6, pos = task & 63;
        int i = pos >> 3, j = pos & 7;
        float2 cs = (m < 32) ? tab[(r0 + prs * 8 + i) * 32 + m]
                             : tab[(pc * 8 + j) * 32 + (m - 32)];
        float sqp = sq[pos], skp = sk[pos];
        float q0 = qs[(2 * m) * CST + pos], q1 = qs[(2 * m + 1) * CST + pos];
        float y0 = gq[2 * m] * q0 * sqp, y1 = gq[2 * m + 1] * q1 * sqp;
        qs[(2 * m) * CST + pos] = y0 * cs.x - y1 * cs.y;
        qs[(2 * m + 1) * CST + pos] = y1 * cs.x + y0 * cs.y;
        float k0 = ks[(2 * m) * CST + pos], k1 = ks[(2 * m + 1) * CST + pos];
        float z0 = gk[2 * m] * k0 * skp, z1 = gk[2 * m + 1] * k1 * skp;
        ks[(2 * m) * CST + pos] = z0 * cs.x - z1 * cs.y;
        ks[(2 * m + 1) * CST + pos] = z1 * cs.x + z0 * cs.y;
    }
    __syncthreads();

    // phase 2: circular conv rows -> registers (task = (c, m), 4 per thread; UNROLLED so creg
    // stays in VGPRs, not scratch)
    float creg[4][8];
#pragma unroll
    for (int g4 = 0; g4 < 4; g4++) {
        int task = g4 * 256 + t;
        int c = task >> 3, m = task & 7;
        float o8[8] = {0, 0, 0, 0, 0, 0, 0, 0};
#pragma unroll
        for (int i = 0; i < 8; i++) {
            const float* qr = &qs[c * CST + i * 8];
            float4 qa = *(const float4*)qr, qb = *(const float4*)(qr + 4);
            float qq[8] = {qa.x, qa.y, qa.z, qa.w, qb.x, qb.y, qb.z, qb.w};
            int kr = (m - i) & 7;
            const float* krp = &ks[c * CST + kr * 8];
            float4 ka = *(const float4*)krp, kb2 = *(const float4*)(krp + 4);
            float kk[8] = {ka.x, ka.y, ka.z, ka.w, kb2.x, kb2.y, kb2.z, kb2.w};
#pragma unroll
            for (int n = 0; n < 8; n++)
#pragma unroll
                for (int j = 0; j < 8; j++)
                    o8[n] = fmaf(qq[j], kk[(n - j) & 7], o8[n]);
        }
#pragma unroll
        for (int n = 0; n < 8; n++) creg[g4][n] = o8[n];
    }
    __syncthreads();

    // phase 3: store corr over qs
#pragma unroll
    for (int g4 = 0; g4 < 4; g4++) {
        int task = g4 * 256 + t;
        int c = task >> 3, m = task & 7;
        *(float4*)&qs[c * CST + m * 8] =
            make_float4(creg[g4][0], creg[g4][1], creg[g4][2], creg[g4][3]);
        *(float4*)&qs[c * CST + m * 8 + 4] =
            make_float4(creg[g4][4], creg[g4][5], creg[g4][6], creg[g4][7]);
    }
    __syncthreads();

    // phase 4: per-position sum of corr^2 over channels
    {
        int pos = t & 63, q4 = t >> 6;
        float ssum = 0.f;
        for (int c = q4 * 32; c < q4 * 32 + 32; c++) {
            float v = qs[c * CST + pos];
            ssum = fmaf(v, v, ssum);
        }
        part[q4 * 64 + pos] = ssum;
    }
    __syncthreads();
    if (t < 64) {
        float s = part[t] + part[64 + t] + part[128 + t] + part[192 + t];
        scal[t] = rsqrtf(s * (1.0f / 128.f) + EPS);
    }
    __syncthreads();

    // phase 5: tmod in place: qs[c][pos] = corr*scal[pos]*gn[c]*v[c][pos]
    for (int it = 0; it < 8; it++) {
        int l4 = it * 256 + t;
        int c = l4 >> 4, r4 = l4 & 15;
        int i = r4 >> 1, jq = r4 & 1;
        float4 vv = *(const float4*)(vg + (size_t)c * SR + i * 256 + jq * 4);
        float4 sc4 = *(const float4*)&scal[r4 * 4];
        float g = gn[c];
        float4 cu = *(float4*)&qs[c * CST + r4 * 4];
        cu.x = cu.x * sc4.x * g * vv.x;
        cu.y = cu.y * sc4.y * g * vv.y;
        cu.z = cu.z * sc4.z * g * vv.z;
        cu.w = cu.w * sc4.w * g * vv.w;
        *(float4*)&qs[c * CST + r4 * 4] = cu;
    }
    __syncthreads();

    // phase 6: project 128->64, stage to ks as out_s[pos*CST + o]
    {
        int o = t & 63, pg = t >> 6;
        float acc[16];
#pragma unroll
        for (int u = 0; u < 16; u++) acc[u] = 0.f;
        for (int c = 0; c < C2; c++) {
            float w = wpt[c * 64 + o];
            const float* tp = &qs[c * CST + pg * 16];
#pragma unroll
            for (int u4 = 0; u4 < 4; u4++) {
                float4 tv = *(const float4*)(tp + u4 * 4);
                acc[u4 * 4 + 0] = fmaf(w, tv.x, acc[u4 * 4 + 0]);
                acc[u4 * 4 + 1] = fmaf(w, tv.y, acc[u4 * 4 + 1]);
                acc[u4 * 4 + 2] = fmaf(w, tv.z, acc[u4 * 4 + 2]);
                acc[u4 * 4 + 3] = fmaf(w, tv.w, acc[u4 * 4 + 3]);
            }
        }
#pragma unroll
        for (int u = 0; u < 16; u++) ks[(pg * 16 + u) * CST + o] = acc[u];
    }
    __syncthreads();

    // phase 7: coalesced out write
    float* og = outb + (size_t)r0 * 256 + sb;
    for (int it = 0; it < 4; it++) {
        int l4 = it * 256 + t;
        int o = l4 >> 4, r4 = l4 & 15;
        int i = r4 >> 1, jq = r4 & 1;
        int p0 = i * 8 + jq * 4;
        float4 vv = make_float4(ks[(p0 + 0) * CST + o], ks[(p0 + 1) * CST + o],
                                ks[(p0 + 2) * CST + o], ks[(p0 + 3) * CST + o]);
        *(float4*)(og + (size_t)o * HW + i * 256 + jq * 4) = vv;
    }
}

extern "C" void kernel_launch(void* const* d_in, const int* in_sizes, int n_in,
                              void* d_out, int out_size, void* d_ws, size_t ws_size,
                              hipStream_t stream) {
    const float* x   = (const float*)d_in[0];
    const float* wh  = (const float*)d_in[1];
    const float* wdw = (const float*)d_in[2];
    const float* wp  = (const float*)d_in[3];
    const float* gn  = (const float*)d_in[4];
    const float* gq  = (const float*)d_in[5];
    const float* gk  = (const float*)d_in[6];
    float* out = (float*)d_out;

    // ws layout (floats): tab[16384] | wpt[8192] | h2s[384 * R * 256]
    size_t avail = ws_size / 4;
    if (avail < (size_t)24576 + (size_t)C6 * 8 * 256) return;  // need at least R=8
    size_t rows_cap = (avail - 24576) / ((size_t)C6 * 256);
    int R = (rows_cap >= 256) ? 256 : (int)(rows_cap & ~(size_t)7);

    float* ws = (float*)d_ws;
    float2* tab = (float2*)ws;
    float* wpt  = ws + 16384;
    float* h2s  = ws + 24576;

    k_tab<<<32, 256, 0, stream>>>(tab);
    k_wt<<<32, 256, 0, stream>>>(wp, wpt);
    for (int b = 0; b < BB; b++) {
        const float* xb = x + (size_t)b * Cc * HW;
        float* outb = out + (size_t)b * Cc * HW;
        for (int r0 = 0; r0 < 256; r0 += R) {
            int Rc = (256 - r0 < R) ? (256 - r0) : R;
            int tiles_y = (Rc + 29) / 30;
            k_expdw<<<19 * tiles_y * OSPLIT, 256, 0, stream>>>(xb, wh, wdw, h2s, r0, Rc, tiles_y);
            k_patch<<<(Rc / 8) * 32, 256, 0, stream>>>(h2s, gq, gk, gn, wpt, tab, outb, r0, Rc);
        }
    }
}